// Round 15
// baseline (734.985 us; speedup 1.0000x reference)
//
#include <hip/hip_runtime.h>
#include <cstdio>

#define B_   64
#define S_   512
#define D_   512
#define H_   8
#define DK_  64
#define DFF_ 1024
#define L_   2
#define BS_  (B_ * S_)   // 32768

typedef __attribute__((ext_vector_type(8))) short bf16x8;
typedef __attribute__((ext_vector_type(4))) short bf16x4;
typedef __attribute__((ext_vector_type(4))) float f32x4;

__device__ inline short f2bf(float f) {
  unsigned u = __float_as_uint(f);
  u = u + 0x7FFF + ((u >> 16) & 1);
  return (short)(u >> 16);
}
__device__ inline float bf2f(short s) {
  return __uint_as_float(((unsigned)(unsigned short)s) << 16);
}

// async global->LDS, 16B per lane; lds dest = wave-uniform base + lane*16
__device__ inline void gl_lds16(const short* g, void* lds_base) {
  __builtin_amdgcn_global_load_lds(
      (const __attribute__((address_space(1))) void*)g,
      (__attribute__((address_space(3))) void*)lds_base, 16, 0, 0);
}

// ---------------- positional encoding table ----------------
__global__ void pe_kernel(float* __restrict__ pe) {
  int idx = blockIdx.x * 256 + threadIdx.x;      // S_*D_ threads
  int s = idx >> 9, d = idx & 511;
  float dv = __expf((float)(d & ~1) * (-9.210340371976184f / (float)D_));
  float ang = (float)s * dv;
  pe[idx] = (d & 1) ? cosf(ang) : sinf(ang);
}

// xb = bf16(q + pe); yb = bf16(qa + pe). 8 elem/thread. (bf16 residual master)
__global__ __launch_bounds__(256) void prep_kernel(
    const float* __restrict__ q, const float* __restrict__ qa,
    const float* __restrict__ pe,
    short* __restrict__ xb, short* __restrict__ yb) {
  size_t base = ((size_t)blockIdx.x * 256 + threadIdx.x) * 8;
  int sd = (int)(base & (size_t)(S_ * D_ - 1));
  f32x4 p0 = *(const f32x4*)(pe + sd);
  f32x4 p1 = *(const f32x4*)(pe + sd + 4);
  f32x4 q0 = *(const f32x4*)(q + base);
  f32x4 q1 = *(const f32x4*)(q + base + 4);
  f32x4 a0 = *(const f32x4*)(qa + base);
  f32x4 a1 = *(const f32x4*)(qa + base + 4);
  bf16x8 xv, yv;
#pragma unroll
  for (int i = 0; i < 4; ++i) {
    xv[i] = f2bf(q0[i] + p0[i]);
    yv[i] = f2bf(a0[i] + p0[i]);
  }
#pragma unroll
  for (int i = 0; i < 4; ++i) {
    xv[4 + i] = f2bf(q1[i] + p1[i]);
    yv[4 + i] = f2bf(a1[i] + p1[i]);
  }
  *(bf16x8*)(xb + base) = xv;
  *(bf16x8*)(yb + base) = yv;
}

// ---------------- all weight transposes in ONE launch ----------------
struct TrArgs {
  const float* src[10];
  short* dst[10];
  int R[10], C[10];
};
__global__ __launch_bounds__(256) void tr_w_all(TrArgs a) {
  const int slot = blockIdx.z;
  const int R = a.R[slot], C = a.C[slot];
  const int c0 = blockIdx.x * 64, r0 = blockIdx.y * 64;
  if (c0 >= C || r0 >= R) return;
  const float* __restrict__ src = a.src[slot];
  short* __restrict__ dst = a.dst[slot];
  __shared__ short Ts[64][72];
  const int t = threadIdx.x;
#pragma unroll
  for (int it = 0; it < 2; ++it) {
    int c2 = it * 256 + t;
    int srow = c2 >> 3, schunk = c2 & 7;
    const float* sp = src + (size_t)(r0 + srow) * C + c0 + schunk * 8;
    f32x4 a0 = *(const f32x4*)sp;
    f32x4 a1 = *(const f32x4*)(sp + 4);
#pragma unroll
    for (int k = 0; k < 4; ++k) Ts[srow][schunk * 8 + k] = f2bf(a0[k]);
#pragma unroll
    for (int k = 0; k < 4; ++k) Ts[srow][schunk * 8 + 4 + k] = f2bf(a1[k]);
  }
  __syncthreads();
#pragma unroll
  for (int it = 0; it < 2; ++it) {
    int c2 = it * 256 + t;
    int orow = c2 >> 3, ochunk = c2 & 7;
    bf16x8 vv;
#pragma unroll
    for (int k = 0; k < 8; ++k) vv[k] = Ts[ochunk * 8 + k][orow];
    *(bf16x8*)(dst + (size_t)(c0 + orow) * R + r0 + ochunk * 8) = vv;
  }
}

// ---------------- bf16 MFMA GEMM: C[M,N] = A[M,K] @ BT[N,K]^T + bias ----------------
// 256x256 tile, BK=64, 8 waves (2Mx4N), phase-split schedule (T3+T4 template):
// per K-tile: entry vmcnt(0)+barrier, stage tile t+1 (8 gl_lds) in phase 0,
// 4 compute phases (m-pair x 4n x 2kk = 16 MFMA each) with setprio + sched pins,
// phase-end barriers. Row-XOR chunk swizzle (pre-swizzled source, rule #21) for
// conflict-free ds_read_b128. Swapped-operand MFMA -> b64 column stores. XCD remap.
__global__ __launch_bounds__(512, 2) void gemm_bt(
    const short* __restrict__ A, const short* __restrict__ BT,
    const float* __restrict__ bias, short* __restrict__ Cb,
    int M, int N, int K, int relu, int bias_row, int nx, int xmaj)
{
  const int nwg = gridDim.x;                 // multiple of 8
  const int cpx = nwg >> 3;
  const int l = (blockIdx.x & 7) * cpx + (blockIdx.x >> 3);
  int bcol, brow;
  if (xmaj) { bcol = l % nx; brow = l / nx; }
  else      { int ny = nwg / nx; brow = l % ny; bcol = l / ny; }

  __shared__ __align__(16) short As[2][256 * 64];
  __shared__ __align__(16) short Bs[2][256 * 64];
  const int t = threadIdx.x;                 // 0..511
  const int w = t >> 6, lane = t & 63, lr = lane & 15, lk = lane >> 4;
  const int wm = w >> 2, wn = w & 3;         // 2 x 4 wave grid

  const f32x4 vzero = {0.f, 0.f, 0.f, 0.f};
  f32x4 acc[8][4];
#pragma unroll
  for (int m = 0; m < 8; ++m)
#pragma unroll
    for (int n = 0; n < 4; ++n) acc[m][n] = vzero;

  const short* Abase = A + (size_t)brow * 256 * K;
  const short* Bbase = BT + (size_t)bcol * 256 * K;

  // stage one half-tile (128 rows x 64 cols) of A or B; linear LDS dest chunks,
  // pre-swizzled SOURCE segment (seg ^ (row&7)) so reads can use the same XOR.
  auto stageH = [&](short* lds, const short* gsrc, int half, int k0) {
#pragma unroll
    for (int it = 0; it < 2; ++it) {
      int c = it * 512 + t;              // chunk in half: 0..1023 (8 chunks/row)
      int cb = it * 512 + w * 64;        // wave-uniform chunk base
      int row = half * 128 + (c >> 3);
      int seg = (c & 7) ^ (row & 7);     // pre-swizzled source segment
      gl_lds16(gsrc + (size_t)row * K + k0 + seg * 8,
               (char*)lds + (size_t)(half * 1024 + cb) * 16);
    }
  };
  // swizzled LDS read of one bf16x8 fragment at (row, col-chunk s)
  auto ldfrag = [&](const short* lds, int row, int s) -> bf16x8 {
    int chunk = row * 8 + (s ^ (row & 7));
    return *(const bf16x8*)((const char*)lds + (size_t)chunk * 16);
  };

  const int T = K >> 6;
  // prologue: stage tile 0 (4 half-tiles, 8 loads/thread)
  stageH(&As[0][0], Abase, 0, 0);
  stageH(&As[0][0], Abase, 1, 0);
  stageH(&Bs[0][0], Bbase, 0, 0);
  stageH(&Bs[0][0], Bbase, 1, 0);

  for (int ti = 0; ti < T; ++ti) {
    const int cbuf = ti & 1, obuf = cbuf ^ 1;
    asm volatile("s_waitcnt vmcnt(0)" ::: "memory");   // tile ti fully landed
    asm volatile("s_barrier" ::: "memory");            // visible to all waves

    // stage tile ti+1 into the other buffer (issued early; consumed next iter)
    if (ti + 1 < T) {
      int k1 = (ti + 1) * 64;
      stageH(&As[obuf][0], Abase, 0, k1);
      stageH(&As[obuf][0], Abase, 1, k1);
      stageH(&Bs[obuf][0], Bbase, 0, k1);
      stageH(&Bs[obuf][0], Bbase, 1, k1);
    }

    // B fragments for this wave (held across phases): 4n x 2kk
    bf16x8 bf[4][2];
#pragma unroll
    for (int n = 0; n < 4; ++n)
#pragma unroll
      for (int kk = 0; kk < 2; ++kk)
        bf[n][kk] = ldfrag(&Bs[cbuf][0], wn * 64 + n * 16 + lr, kk * 4 + lk);

    // 4 compute phases: m-pair x all-n x kk0,1 = 16 MFMA each
#pragma unroll
    for (int p = 0; p < 4; ++p) {
      bf16x8 af[2][2];
#pragma unroll
      for (int mm = 0; mm < 2; ++mm)
#pragma unroll
        for (int kk = 0; kk < 2; ++kk)
          af[mm][kk] = ldfrag(&As[cbuf][0], wm * 128 + (p * 2 + mm) * 16 + lr, kk * 4 + lk);
      __builtin_amdgcn_sched_barrier(0);
      __builtin_amdgcn_s_setprio(1);
#pragma unroll
      for (int mm = 0; mm < 2; ++mm)
#pragma unroll
        for (int n = 0; n < 4; ++n)
#pragma unroll
          for (int kk = 0; kk < 2; ++kk)
            acc[p * 2 + mm][n] = __builtin_amdgcn_mfma_f32_16x16x32_bf16(
                bf[n][kk], af[mm][kk], acc[p * 2 + mm][n], 0, 0, 0);
      __builtin_amdgcn_s_setprio(0);
      __builtin_amdgcn_sched_barrier(0);
      asm volatile("s_barrier" ::: "memory");          // phase-end lockstep
    }
  }

#pragma unroll
  for (int m = 0; m < 8; ++m) {
    int row = brow * 256 + wm * 128 + m * 16 + lr;
    float brv = (bias && bias_row) ? bias[row] : 0.f;
    size_t rb = (size_t)row * N;
#pragma unroll
    for (int n = 0; n < 4; ++n) {
      int colb = bcol * 256 + wn * 64 + n * 16 + lk * 4;
      f32x4 bv4;
      if (bias && !bias_row) bv4 = *(const f32x4*)(bias + colb);
      else { bv4[0] = brv; bv4[1] = brv; bv4[2] = brv; bv4[3] = brv; }
      bf16x4 ov;
#pragma unroll
      for (int j = 0; j < 4; ++j) {
        float vv = acc[m][n][j] + bv4[j];
        if (relu) vv = fmaxf(vv, 0.f);
        ov[j] = f2bf(vv);
      }
      *(bf16x4*)(Cb + rb + colb) = ov;   // 8B store, 4 lanes/row contiguous 32B
    }
  }
}

// ---------------- fused attention (best-measured r11 variant) ----------------
template<int P>
__device__ __forceinline__ void attn_body(
    const short* __restrict__ qk, const short* __restrict__ vT,
    const float* __restrict__ fr, short* __restrict__ out,
    short (*Pl)[552], float (*redsum)[32][4],
    int h, int b, int w, int lr, int lk)
{
  constexpr int qo0 = 32 * P, qo1 = 32 * (15 - P);
  constexpr int c0 = 2 * P + 2;          // tile0 fragment count
  constexpr int colb1 = c0 * 16;         // tile1 P-column offset
  constexpr int n0 = P + 1;              // unit0 PV kb count
  constexpr int n1 = 16 - P;             // unit1 PV kb count

  const size_t qk_head = (size_t)b * S_ * D_ + (size_t)h * DK_;
  const float scale = 0.125f;   // 1/sqrt(64)

  bf16x8 qf0[2][2], qf1[2][2];   // [qt][ks]
#pragma unroll
  for (int qt = 0; qt < 2; ++qt)
#pragma unroll
    for (int ks = 0; ks < 2; ++ks) {
      qf0[qt][ks] = *(const bf16x8*)(qk + qk_head + (size_t)(qo0 + qt * 16 + lr) * D_ + ks * 32 + lk * 8);
      qf1[qt][ks] = *(const bf16x8*)(qk + qk_head + (size_t)(qo1 + qt * 16 + lr) * D_ + ks * 32 + lk * 8);
    }

  float frv0[2], frv1[2];
#pragma unroll
  for (int qt = 0; qt < 2; ++qt) {
    frv0[qt] = scale * fr[(size_t)b * S_ + qo0 + qt * 16 + lr];
    frv1[qt] = scale * fr[(size_t)b * S_ + qo1 + qt * 16 + lr];
  }

  const f32x4 vzero = {0.f, 0.f, 0.f, 0.f};
  f32x4 acc[9][2];
#pragma unroll
  for (int i = 0; i < 9; ++i) { acc[i][0] = vzero; acc[i][1] = vzero; }

  // ---- QK^T (swapped), ring-4 K prefetch
  const int nfr = (w < 2) ? 9 : 8;     // 34 fragments over 4 waves
  const short* kqbase = qk + qk_head + (size_t)lr * D_ + lk * 8;
  auto kfoff = [&](int i) -> size_t {
    int f = w + 4 * i;
    int kt = (f < c0) ? f : f - c0;
    return (size_t)kt * 16 * D_;
  };
  bf16x8 kreg[4][2];
#pragma unroll
  for (int i = 0; i < 4; ++i) {
    if (i < nfr) {
      const short* p = kqbase + kfoff(i);
      kreg[i][0] = *(const bf16x8*)p;
      kreg[i][1] = *(const bf16x8*)(p + 32);
    }
  }
  __builtin_amdgcn_sched_barrier(0);
#pragma unroll
  for (int i = 0; i < 9; ++i) {
    if (i < nfr) {
      const int f = w + 4 * i;
      __builtin_amdgcn_s_setprio(1);
      if (f < c0) {
#pragma unroll
        for (int ks = 0; ks < 2; ++ks) {
          acc[i][0] = __builtin_amdgcn_mfma_f32_16x16x32_bf16(kreg[i & 3][ks], qf0[0][ks], acc[i][0], 0, 0, 0);
          acc[i][1] = __builtin_amdgcn_mfma_f32_16x16x32_bf16(kreg[i & 3][ks], qf0[1][ks], acc[i][1], 0, 0, 0);
        }
      } else {
#pragma unroll
        for (int ks = 0; ks < 2; ++ks) {
          acc[i][0] = __builtin_amdgcn_mfma_f32_16x16x32_bf16(kreg[i & 3][ks], qf1[0][ks], acc[i][0], 0, 0, 0);
          acc[i][1] = __builtin_amdgcn_mfma_f32_16x16x32_bf16(kreg[i & 3][ks], qf1[1][ks], acc[i][1], 0, 0, 0);
        }
      }
      __builtin_amdgcn_s_setprio(0);
      __builtin_amdgcn_sched_barrier(0); // MFMAs(i) before refill of slot i&3
      if (i + 4 < nfr) {
        const short* p = kqbase + kfoff(i + 4);
        kreg[i & 3][0] = *(const bf16x8*)p;
        kreg[i & 3][1] = *(const bf16x8*)(p + 32);
      }
      __builtin_amdgcn_sched_barrier(0);
    }
  }

  // ---- PV V-prologue: V(0..2) for both units issued NOW (hidden under exp) ----
  const int uqt0 = w & 1, udh0 = w >> 1;
  const int uqt1 = w >> 1, udh1 = w & 1;
  const short* vu0 = vT + (size_t)(h * DK_ + udh0 * 32 + lr) * BS_ + (size_t)b * S_ + lk * 8;
  const short* vu1 = vT + (size_t)(h * DK_ + udh1 * 32 + lr) * BS_ + (size_t)b * S_ + lk * 8;
  bf16x8 vfB[3][2][2];    // [slot][unit][n], slot = kb % 3
#pragma unroll
  for (int kb = 0; kb < 3; ++kb) {
    if (kb < n0) {
#pragma unroll
      for (int n = 0; n < 2; ++n)
        vfB[kb][0][n] = *(const bf16x8*)(vu0 + (size_t)n * 16 * BS_ + kb * 32);
    }
    if (kb < n1) {
#pragma unroll
      for (int n = 0; n < 2; ++n)
        vfB[kb][1][n] = *(const bf16x8*)(vu1 + (size_t)n * 16 * BS_ + kb * 32);
    }
  }
  __builtin_amdgcn_sched_barrier(0);     // V loads in flight before exp pass

  // ---- exp pass: e = (k < q) ? exp(score*frv) : 0 ; b64 P-writes; row sums
  float rs00 = 0.f, rs01 = 0.f, rs10 = 0.f, rs11 = 0.f;
#pragma unroll
  for (int frag = 0; frag < 34; ++frag) {
    if ((frag & 3) == w) {
      const int i = frag >> 2;
      const int tl = (frag < c0) ? 0 : 1;              // compile-time
      const int kt = tl ? frag - c0 : frag;
      const int kbase = kt * 16 + lk * 4;
      const int colb = (tl ? colb1 : 0) + kbase;
#pragma unroll
      for (int qt = 0; qt < 2; ++qt) {
        int qrow = (tl ? qo1 : qo0) + qt * 16 + lr;
        float fv = tl ? frv1[qt] : frv0[qt];
        bf16x4 pk;
        float rs = 0.f;
#pragma unroll
        for (int j = 0; j < 4; ++j) {
          float e = (kbase + j < qrow) ? __expf(acc[i][qt][j] * fv) : 0.f;
          rs += e;
          pk[j] = f2bf(e);
        }
        *(bf16x4*)&Pl[qt * 16 + lr][colb] = pk;
        if (tl == 0) { if (qt == 0) rs00 += rs; else rs01 += rs; }
        else         { if (qt == 0) rs10 += rs; else rs11 += rs; }
      }
    }
  }

#pragma unroll
  for (int msk = 16; msk < 64; msk <<= 1) {
    rs00 += __shfl_xor(rs00, msk);
    rs01 += __shfl_xor(rs01, msk);
    rs10 += __shfl_xor(rs10, msk);
    rs11 += __shfl_xor(rs11, msk);
  }
  if (lk == 0) {
    redsum[0][lr][w] = rs00;
    redsum[0][16 + lr][w] = rs01;
    redsum[1][lr][w] = rs10;
    redsum[1][16 + lr][w] = rs11;
  }
  __syncthreads();   // P + redsum ready (single barrier)

  // ---- PV: ring-3 V pipeline + 1-deep pa(LDS) prefetch ----
  const short* prow0 = &Pl[uqt0 * 16 + lr][lk * 8];
  const short* prow1 = &Pl[uqt1 * 16 + lr][colb1 + lk * 8];
  f32x4 oacc0[2] = {vzero, vzero}, oacc1[2] = {vzero, vzero};
  bf16x8 paB[2][2];       // [parity][unit]
  paB[0][0] = *(const bf16x8*)prow0;
  paB[0][1] = *(const bf16x8*)prow1;

#pragma unroll
  for (int kb = 0; kb < 16; ++kb) {
    const int sc = kb % 3, pc = kb & 1, pn = pc ^ 1;
    if (kb + 1 < n0) paB[pn][0] = *(const bf16x8*)(prow0 + (kb + 1) * 32);
    if (kb + 1 < n1) paB[pn][1] = *(const bf16x8*)(prow1 + (kb + 1) * 32);
    __builtin_amdgcn_sched_barrier(0);
    __builtin_amdgcn_s_setprio(1);
    if (kb < n0) {
#pragma unroll
      for (int n = 0; n < 2; ++n)
        oacc0[n] = __builtin_amdgcn_mfma_f32_16x16x32_bf16(paB[pc][0], vfB[sc][0][n], oacc0[n], 0, 0, 0);
    }
    if (kb < n1) {
#pragma unroll
      for (int n = 0; n < 2; ++n)
        oacc1[n] = __builtin_amdgcn_mfma_f32_16x16x32_bf16(paB[pc][1], vfB[sc][1][n], oacc1[n], 0, 0, 0);
    }
    __builtin_amdgcn_s_setprio(0);
    __builtin_amdgcn_sched_barrier(0);
    if (kb + 3 < n0) {
#pragma unroll
      for (int n = 0; n < 2; ++n)
        vfB[sc][0][n] = *(const bf16x8*)(vu0 + (size_t)n * 16 * BS_ + (kb + 3) * 32);
    }
    if (kb + 3 < n1) {
#pragma unroll
      for (int n = 0; n < 2; ++n)
        vfB[sc][1][n] = *(const bf16x8*)(vu1 + (size_t)n * 16 * BS_ + (kb + 3) * 32);
    }
    __builtin_amdgcn_sched_barrier(0);
  }

  // ---- normalize + write
  {
    float invd[4];
#pragma unroll
    for (int j = 0; j < 4; ++j) {
      int row = uqt0 * 16 + lk * 4 + j;
      float ds = redsum[0][row][0] + redsum[0][row][1] + redsum[0][row][2] + redsum[0][row][3];
      invd[j] = ds > 0.f ? 1.f / ds : 0.f;
    }
#pragma unroll
    for (int n = 0; n < 2; ++n)
#pragma unroll
      for (int j = 0; j < 4; ++j) {
        int qrow = qo0 + uqt0 * 16 + lk * 4 + j;
        out[qk_head + (size_t)qrow * D_ + udh0 * 32 + n * 16 + lr] = f2bf(oacc0[n][j] * invd[j]);
      }
  }
  {
    float invd[4];
#pragma unroll
    for (int j = 0; j < 4; ++j) {
      int row = uqt1 * 16 + lk * 4 + j;
      float ds = redsum[1][row][0] + redsum[1][row][1] + redsum[1][row][2] + redsum[1][row][3];
      invd[j] = ds > 0.f ? 1.f / ds : 0.f;
    }
#pragma unroll
    for (int n = 0; n < 2; ++n)
#pragma unroll
      for (int j = 0; j < 4; ++j) {
        int qrow = qo1 + uqt1 * 16 + lk * 4 + j;
        out[qk_head + (size_t)qrow * D_ + udh1 * 32 + n * 16 + lr] = f2bf(oacc1[n][j] * invd[j]);
      }
  }
}

__global__ __launch_bounds__(256, 3) void attn_kernel(
    const short* __restrict__ qk, const short* __restrict__ vT,
    const float* __restrict__ fr, short* __restrict__ out)
{
  const int hw = blockIdx.x;                 // 4096 blocks
  const int l = (hw & 7) * 512 + (hw >> 3);  // bijective XCD grouping
  const int p = l & 7, hb = l >> 3;
  const int h = hb & 7, b = hb >> 3;
  const int t = threadIdx.x;
  const int w = t >> 6, lr = t & 15, lk = (t & 63) >> 4;

  __shared__ __align__(16) short Pl[32][552];
  __shared__ __align__(16) float redsum[2][32][4];

  switch (p) {
    case 0: attn_body<0>(qk, vT, fr, out, Pl, redsum, h, b, w, lr, lk); break;
    case 1: attn_body<1>(qk, vT, fr, out, Pl, redsum, h, b, w, lr, lk); break;
    case 2: attn_body<2>(qk, vT, fr, out, Pl, redsum, h, b, w, lr, lk); break;
    case 3: attn_body<3>(qk, vT, fr, out, Pl, redsum, h, b, w, lr, lk); break;
    case 4: attn_body<4>(qk, vT, fr, out, Pl, redsum, h, b, w, lr, lk); break;
    case 5: attn_body<5>(qk, vT, fr, out, Pl, redsum, h, b, w, lr, lk); break;
    case 6: attn_body<6>(qk, vT, fr, out, Pl, redsum, h, b, w, lr, lk); break;
    case 7: attn_body<7>(qk, vT, fr, out, Pl, redsum, h, b, w, lr, lk); break;
  }
}

// ---------------- fused residual + LayerNorm (bf16 master) ----------------
template<int FINAL>
__global__ __launch_bounds__(256) void ln_res_t(
    const short* __restrict__ xin, const short* __restrict__ add,
    const float* __restrict__ g, const float* __restrict__ bb,
    short* __restrict__ xbout, float* __restrict__ fout)
{
  const int row = blockIdx.x * 4 + (threadIdx.x >> 6);
  const int lane = threadIdx.x & 63;
  const size_t base = (size_t)row * D_ + lane * 8;

  bf16x8 xv = *(const bf16x8*)(xin + base);
  bf16x8 av = *(const bf16x8*)(add + base);
  float vals[8];
#pragma unroll
  for (int i = 0; i < 8; ++i) vals[i] = bf2f(xv[i]) + bf2f(av[i]);

  float s = 0.f, sq = 0.f;
#pragma unroll
  for (int i = 0; i < 8; ++i) { s += vals[i]; sq += vals[i] * vals[i]; }
#pragma unroll
  for (int m = 1; m < 64; m <<= 1) { s += __shfl_xor(s, m); sq += __shfl_xor(sq, m); }

  float mean = s * (1.f / D_);
  float var = sq * (1.f / D_) - mean * mean;
  float rstd = rsqrtf(var + 1e-5f);

  int col = lane * 8;
  if (FINAL) {
    f32x4 o0, o1;
#pragma unroll
    for (int i = 0; i < 8; ++i) {
      float vv = g[col + i] * (vals[i] - mean) * rstd + bb[col + i];
      if (i < 4) o0[i] = vv; else o1[i - 4] = vv;
    }
    *(f32x4*)(fout + base) = o0;
    *(f32x4*)(fout + base + 4) = o1;
  } else {
    bf16x8 ob;
#pragma unroll
    for (int i = 0; i < 8; ++i)
      ob[i] = f2bf(g[col + i] * (vals[i] - mean) * rstd + bb[col + i]);
    *(bf16x8*)(xbout + base) = ob;
  }
}

// ---------------- host ----------------
extern "C" void kernel_launch(void* const* d_in, const int* in_sizes, int n_in,
                              void* d_out, int out_size, void* d_ws, size_t ws_size,
                              hipStream_t stream) {
  const float* q_emb = (const float*)d_in[0];
  const float* qa_emb = (const float*)d_in[1];
  const float* frate = (const float*)d_in[2];
  const float* Wk = (const float*)d_in[3];
  const float* bk = (const float*)d_in[4];
  const float* Wv = (const float*)d_in[5];
  const float* bv = (const float*)d_in[6];
  const float* Wo = (const float*)d_in[7];
  const float* bo = (const float*)d_in[8];
  const float* ln1g = (const float*)d_in[9];
  const float* ln1b = (const float*)d_in[10];
  const float* W1 = (const float*)d_in[11];
  const float* b1 = (const float*)d_in[12];
  const float* W2 = (const float*)d_in[13];
  const float* b2 = (const float*)d_in[14];
  const float* ln2g = (const float*)d_in[15];
  const float* ln2b = (const float*)d_in[16];
  float* x = (float*)d_out;

  char* ws = (char*)d_ws;
  size_t off = 0;
  auto alloc = [&](size_t bytes) -> void* {
    void* p = ws + off;
    off += (bytes + 255) & ~(size_t)255;
    return p;
  };
  const size_t MTOK = (size_t)BS_;   // 32768 rows
  float* pe    = (float*)alloc((size_t)S_ * D_ * 4);
  short* xb    = (short*)alloc(MTOK * D_ * 2);
  short* yb    = (short*)alloc(MTOK * D_ * 2);
  short* qkb   = (short*)alloc(MTOK * D_ * 2);
  short* vTb   = (short*)alloc(MTOK * D_ * 2);   // V transposed: [D][B*S]
  short* ff1b  = (short*)alloc(MTOK * DFF_ * 2);
  short* attnb = ff1b;
  short* goutb = qkb;
  short* wT[L_][5];
  for (int i = 0; i < L_; ++i) {
    wT[i][0] = (short*)alloc((size_t)D_ * D_ * 2);     // WkT [D][D]
    wT[i][1] = (short*)alloc((size_t)D_ * D_ * 2);     // WvT
    wT[i][2] = (short*)alloc((size_t)D_ * D_ * 2);     // WoT
    wT[i][3] = (short*)alloc((size_t)D_ * DFF_ * 2);   // W1T [DFF][D]
    wT[i][4] = (short*)alloc((size_t)DFF_ * D_ * 2);   // W2T [D][DFF]
  }
  if (off > ws_size) {
    fprintf(stderr, "parKT: workspace overflow: need %zu have %zu\n", off, ws_size);
    return;
  }

  pe_kernel<<<(S_ * D_) / 256, 256, 0, stream>>>(pe);
  prep_kernel<<<(int)(MTOK * D_ / (256 * 8)), 256, 0, stream>>>(q_emb, qa_emb, pe, xb, yb);

  TrArgs ta;
  for (int i = 0; i < L_; ++i) {
    ta.src[i * 5 + 0] = Wk + (size_t)i * D_ * D_;  ta.dst[i * 5 + 0] = wT[i][0]; ta.R[i * 5 + 0] = D_;   ta.C[i * 5 + 0] = D_;
    ta.src[i * 5 + 1] = Wv + (size_t)i * D_ * D_;  ta.dst[i * 5 + 1] = wT[i][1]; ta.R[i * 5 + 1] = D_;   ta.C[i * 5 + 1] = D_;
    ta.src[i * 5 + 2] = Wo + (size_t)i * D_ * D_;  ta.dst[i * 5 + 2] = wT[i][2]; ta.R[i * 5 + 2] = D_;   ta.C[i * 5 + 2] = D_;
    ta.src[i * 5 + 3] = W1 + (size_t)i * D_ * DFF_; ta.dst[i * 5 + 3] = wT[i][3]; ta.R[i * 5 + 3] = D_;   ta.C[i * 5 + 3] = DFF_;
    ta.src[i * 5 + 4] = W2 + (size_t)i * DFF_ * D_; ta.dst[i * 5 + 4] = wT[i][4]; ta.R[i * 5 + 4] = DFF_; ta.C[i * 5 + 4] = D_;
  }
  tr_w_all<<<dim3(DFF_ / 64, DFF_ / 64, 10), 256, 0, stream>>>(ta);

  const int M = (int)MTOK;
  for (int i = 0; i < L_; ++i) {
    // qk = x @ Wk + bk: grid (M/256)*(D/256), A-panel sharing -> xmaj=1, nx=D/256
    gemm_bt<<<(M / 256) * (D_ / 256), 512, 0, stream>>>(xb, wT[i][0], bk + (size_t)i * D_, qkb, M, D_, D_, 0, 0, D_ / 256, 1);
    // vT = WvT @ y^T + bv (bias per row): [D][B*S]; yb-panel sharing -> xmaj=0, nx=#bcol=M/256
    gemm_bt<<<(D_ / 256) * (M / 256), 512, 0, stream>>>(wT[i][1], yb, bv + (size_t)i * D_, vTb, D_, M, D_, 0, 1, M / 256, 0);
    attn_kernel<<<(S_ / 64) * H_ * B_, 256, 0, stream>>>(qkb, vTb, frate, attnb);
    gemm_bt<<<(M / 256) * (D_ / 256), 512, 0, stream>>>(attnb, wT[i][2], bo + (size_t)i * D_, goutb, M, D_, D_, 0, 0, D_ / 256, 1);
    ln_res_t<0><<<M / 4, 256, 0, stream>>>(xb, goutb, ln1g + (size_t)i * D_, ln1b + (size_t)i * D_, xb, nullptr);
    gemm_bt<<<(M / 256) * (DFF_ / 256), 512, 0, stream>>>(xb, wT[i][3], b1 + (size_t)i * DFF_, ff1b, M, DFF_, D_, 1, 0, DFF_ / 256, 1);
    gemm_bt<<<(M / 256) * (D_ / 256), 512, 0, stream>>>(ff1b, wT[i][4], b2 + (size_t)i * D_, goutb, M, D_, DFF_, 0, 0, D_ / 256, 1);
    if (i == L_ - 1)
      ln_res_t<1><<<M / 4, 256, 0, stream>>>(xb, goutb, ln2g + (size_t)i * D_, ln2b + (size_t)i * D_, nullptr, x);
    else
      ln_res_t<0><<<M / 4, 256, 0, stream>>>(xb, goutb, ln2g + (size_t)i * D_, ln2b + (size_t)i * D_, xb, nullptr);
  }
}

// Round 16
// 727.735 us; speedup vs baseline: 1.0100x; 1.0100x over previous
//
#include <hip/hip_runtime.h>
#include <cstdio>

#define B_   64
#define S_   512
#define D_   512
#define H_   8
#define DK_  64
#define DFF_ 1024
#define L_   2
#define BS_  (B_ * S_)   // 32768

typedef __attribute__((ext_vector_type(8))) short bf16x8;
typedef __attribute__((ext_vector_type(4))) short bf16x4;
typedef __attribute__((ext_vector_type(4))) float f32x4;

__device__ inline short f2bf(float f) {
  unsigned u = __float_as_uint(f);
  u = u + 0x7FFF + ((u >> 16) & 1);
  return (short)(u >> 16);
}
__device__ inline float bf2f(short s) {
  return __uint_as_float(((unsigned)(unsigned short)s) << 16);
}

// async global->LDS, 16B per lane; lds dest = wave-uniform base + lane*16
__device__ inline void gl_lds16(const short* g, void* lds_base) {
  __builtin_amdgcn_global_load_lds(
      (const __attribute__((address_space(1))) void*)g,
      (__attribute__((address_space(3))) void*)lds_base, 16, 0, 0);
}

// ---------------- positional encoding table ----------------
__global__ void pe_kernel(float* __restrict__ pe) {
  int idx = blockIdx.x * 256 + threadIdx.x;      // S_*D_ threads
  int s = idx >> 9, d = idx & 511;
  float dv = __expf((float)(d & ~1) * (-9.210340371976184f / (float)D_));
  float ang = (float)s * dv;
  pe[idx] = (d & 1) ? cosf(ang) : sinf(ang);
}

// xb = bf16(q + pe); yb = bf16(qa + pe). 8 elem/thread. (bf16 residual master)
__global__ __launch_bounds__(256) void prep_kernel(
    const float* __restrict__ q, const float* __restrict__ qa,
    const float* __restrict__ pe,
    short* __restrict__ xb, short* __restrict__ yb) {
  size_t base = ((size_t)blockIdx.x * 256 + threadIdx.x) * 8;
  int sd = (int)(base & (size_t)(S_ * D_ - 1));
  f32x4 p0 = *(const f32x4*)(pe + sd);
  f32x4 p1 = *(const f32x4*)(pe + sd + 4);
  f32x4 q0 = *(const f32x4*)(q + base);
  f32x4 q1 = *(const f32x4*)(q + base + 4);
  f32x4 a0 = *(const f32x4*)(qa + base);
  f32x4 a1 = *(const f32x4*)(qa + base + 4);
  bf16x8 xv, yv;
#pragma unroll
  for (int i = 0; i < 4; ++i) {
    xv[i] = f2bf(q0[i] + p0[i]);
    yv[i] = f2bf(a0[i] + p0[i]);
  }
#pragma unroll
  for (int i = 0; i < 4; ++i) {
    xv[4 + i] = f2bf(q1[i] + p1[i]);
    yv[4 + i] = f2bf(a1[i] + p1[i]);
  }
  *(bf16x8*)(xb + base) = xv;
  *(bf16x8*)(yb + base) = yv;
}

// ---------------- all weight transposes in ONE launch ----------------
struct TrArgs {
  const float* src[10];
  short* dst[10];
  int R[10], C[10];
};
__global__ __launch_bounds__(256) void tr_w_all(TrArgs a) {
  const int slot = blockIdx.z;
  const int R = a.R[slot], C = a.C[slot];
  const int c0 = blockIdx.x * 64, r0 = blockIdx.y * 64;
  if (c0 >= C || r0 >= R) return;
  const float* __restrict__ src = a.src[slot];
  short* __restrict__ dst = a.dst[slot];
  __shared__ short Ts[64][72];
  const int t = threadIdx.x;
#pragma unroll
  for (int it = 0; it < 2; ++it) {
    int c2 = it * 256 + t;
    int srow = c2 >> 3, schunk = c2 & 7;
    const float* sp = src + (size_t)(r0 + srow) * C + c0 + schunk * 8;
    f32x4 a0 = *(const f32x4*)sp;
    f32x4 a1 = *(const f32x4*)(sp + 4);
#pragma unroll
    for (int k = 0; k < 4; ++k) Ts[srow][schunk * 8 + k] = f2bf(a0[k]);
#pragma unroll
    for (int k = 0; k < 4; ++k) Ts[srow][schunk * 8 + 4 + k] = f2bf(a1[k]);
  }
  __syncthreads();
#pragma unroll
  for (int it = 0; it < 2; ++it) {
    int c2 = it * 256 + t;
    int orow = c2 >> 3, ochunk = c2 & 7;
    bf16x8 vv;
#pragma unroll
    for (int k = 0; k < 8; ++k) vv[k] = Ts[ochunk * 8 + k][orow];
    *(bf16x8*)(dst + (size_t)(c0 + orow) * R + r0 + ochunk * 8) = vv;
  }
}

// ---------------- bf16 MFMA GEMM (dual-slot): C[M,N] = A[M,K] @ BT[N,K]^T + bias --
// 128x256 tile, BK=32, triple-buffered LDS, ONE barrier per K-step, counted
// vmcnt(6), T2 seg-swizzle (pre-swizzled source, rule #21), swapped-operand MFMA
// (b64 column stores), XCD-aware 1D remap over the COMBINED grid. Two independent
// GEMMs may share one dispatch (second slot may be empty, nblk=0) so their
// prologue drains / ramps / tails overlap.
struct GArgs {
  const short* A; const short* BT; const float* bias; short* Cb;
  int M, N, K, relu, bias_row, nx, xmaj, nblk;
};
__global__ __launch_bounds__(256, 2) void gemm_bt2(GArgs g0, GArgs g1)
{
  const int nwg = gridDim.x;                 // multiple of 8
  const int cpx = nwg >> 3;
  const int l = (blockIdx.x & 7) * cpx + (blockIdx.x >> 3);

  const short* A; const short* BT; const float* bias; short* Cb;
  int M, N, K, relu, bias_row, nx, xmaj, ll;
  if (l < g0.nblk) {
    A = g0.A; BT = g0.BT; bias = g0.bias; Cb = g0.Cb;
    M = g0.M; N = g0.N; K = g0.K; relu = g0.relu; bias_row = g0.bias_row;
    nx = g0.nx; xmaj = g0.xmaj; ll = l;
  } else {
    A = g1.A; BT = g1.BT; bias = g1.bias; Cb = g1.Cb;
    M = g1.M; N = g1.N; K = g1.K; relu = g1.relu; bias_row = g1.bias_row;
    nx = g1.nx; xmaj = g1.xmaj; ll = l - g0.nblk;
  }
  const int nb = (l < g0.nblk) ? g0.nblk : g1.nblk;
  int bcol, brow;
  if (xmaj) { bcol = ll % nx; brow = ll / nx; }
  else      { int ny = nb / nx; brow = ll % ny; bcol = ll / ny; }

  __shared__ __align__(16) short As[3][128][32];
  __shared__ __align__(16) short Bs[3][256][32];
  const int t = threadIdx.x;
  const int w = t >> 6, lane = t & 63, lr = lane & 15, lk = lane >> 4;
  const int wr = w >> 1, wc = w & 1;   // wave: rows wr*64+, cols wc*128+
  const int sw = (lr >> 1) & 3;        // T2 read-chunk swizzle

  const f32x4 vzero = {0.f, 0.f, 0.f, 0.f};
  f32x4 acc[4][8];
#pragma unroll
  for (int m = 0; m < 4; ++m)
#pragma unroll
    for (int n = 0; n < 8; ++n) acc[m][n] = vzero;

  const short* Abase = A + (size_t)brow * 128 * K;
  const short* Bbase = BT + (size_t)bcol * 256 * K;

  // stage with pre-swizzled global source: LDS[row][seg] <- global chunk seg^((row>>1)&3)
  auto stage = [&](int buf, int k0) {   // 6 gl_lds per thread (A:2, B:4)
#pragma unroll
    for (int it = 0; it < 2; ++it) {
      int cb = it * 256 + w * 64;
      int c = cb + lane;
      int row = c >> 2, seg = c & 3;
      int segg = seg ^ ((row >> 1) & 3);
      gl_lds16(Abase + (size_t)row * K + k0 + segg * 8, (char*)&As[buf][0][0] + (size_t)cb * 16);
    }
#pragma unroll
    for (int it = 0; it < 4; ++it) {
      int cb = it * 256 + w * 64;
      int c = cb + lane;
      int row = c >> 2, seg = c & 3;
      int segg = seg ^ ((row >> 1) & 3);
      gl_lds16(Bbase + (size_t)row * K + k0 + segg * 8, (char*)&Bs[buf][0][0] + (size_t)cb * 16);
    }
  };

  const int ntiles = K >> 5;
  stage(0, 0);
  if (ntiles > 1) stage(1, 32);
  int cur = 0, nxt = 2;                    // buffer indices mod 3
  for (int ti = 0; ti < ntiles; ++ti) {
    if (ti + 1 < ntiles) {
      asm volatile("s_waitcnt vmcnt(6)" ::: "memory");   // tile ti landed (ti+1 flying)
    } else {
      asm volatile("s_waitcnt vmcnt(0)" ::: "memory");
    }
    asm volatile("s_barrier" ::: "memory");              // tile ti visible to all waves

    if (ti + 2 < ntiles) stage(nxt, (ti + 2) * 32);      // after barrier: WAR-safe

    bf16x8 af[4], bf[8];
#pragma unroll
    for (int m = 0; m < 4; ++m) af[m] = *(const bf16x8*)&As[cur][wr * 64 + m * 16 + lr][(lk ^ sw) * 8];
#pragma unroll
    for (int n = 0; n < 8; ++n) bf[n] = *(const bf16x8*)&Bs[cur][wc * 128 + n * 16 + lr][(lk ^ sw) * 8];
#pragma unroll
    for (int m = 0; m < 4; ++m)
#pragma unroll
      for (int n = 0; n < 8; ++n)
        acc[m][n] = __builtin_amdgcn_mfma_f32_16x16x32_bf16(bf[n], af[m], acc[m][n], 0, 0, 0);

    cur = (cur == 2) ? 0 : cur + 1;
    nxt = (nxt == 2) ? 0 : nxt + 1;
  }

#pragma unroll
  for (int m = 0; m < 4; ++m) {
    int row = brow * 128 + wr * 64 + m * 16 + lr;
    float brv = (bias && bias_row) ? bias[row] : 0.f;
    size_t rb = (size_t)row * N;
#pragma unroll
    for (int n = 0; n < 8; ++n) {
      int colb = bcol * 256 + wc * 128 + n * 16 + lk * 4;
      f32x4 bv4;
      if (bias && !bias_row) bv4 = *(const f32x4*)(bias + colb);
      else { bv4[0] = brv; bv4[1] = brv; bv4[2] = brv; bv4[3] = brv; }
      bf16x4 ov;
#pragma unroll
      for (int j = 0; j < 4; ++j) {
        float vv = acc[m][n][j] + bv4[j];
        if (relu) vv = fmaxf(vv, 0.f);
        ov[j] = f2bf(vv);
      }
      *(bf16x4*)(Cb + rb + colb) = ov;   // 8B store, 4 lanes/row contiguous 32B
    }
  }
}

// ---------------- fused attention (best-measured r11 variant) ----------------
template<int P>
__device__ __forceinline__ void attn_body(
    const short* __restrict__ qk, const short* __restrict__ vT,
    const float* __restrict__ fr, short* __restrict__ out,
    short (*Pl)[552], float (*redsum)[32][4],
    int h, int b, int w, int lr, int lk)
{
  constexpr int qo0 = 32 * P, qo1 = 32 * (15 - P);
  constexpr int c0 = 2 * P + 2;          // tile0 fragment count
  constexpr int colb1 = c0 * 16;         // tile1 P-column offset
  constexpr int n0 = P + 1;              // unit0 PV kb count
  constexpr int n1 = 16 - P;             // unit1 PV kb count

  const size_t qk_head = (size_t)b * S_ * D_ + (size_t)h * DK_;
  const float scale = 0.125f;   // 1/sqrt(64)

  bf16x8 qf0[2][2], qf1[2][2];   // [qt][ks]
#pragma unroll
  for (int qt = 0; qt < 2; ++qt)
#pragma unroll
    for (int ks = 0; ks < 2; ++ks) {
      qf0[qt][ks] = *(const bf16x8*)(qk + qk_head + (size_t)(qo0 + qt * 16 + lr) * D_ + ks * 32 + lk * 8);
      qf1[qt][ks] = *(const bf16x8*)(qk + qk_head + (size_t)(qo1 + qt * 16 + lr) * D_ + ks * 32 + lk * 8);
    }

  float frv0[2], frv1[2];
#pragma unroll
  for (int qt = 0; qt < 2; ++qt) {
    frv0[qt] = scale * fr[(size_t)b * S_ + qo0 + qt * 16 + lr];
    frv1[qt] = scale * fr[(size_t)b * S_ + qo1 + qt * 16 + lr];
  }

  const f32x4 vzero = {0.f, 0.f, 0.f, 0.f};
  f32x4 acc[9][2];
#pragma unroll
  for (int i = 0; i < 9; ++i) { acc[i][0] = vzero; acc[i][1] = vzero; }

  // ---- QK^T (swapped), ring-4 K prefetch
  const int nfr = (w < 2) ? 9 : 8;     // 34 fragments over 4 waves
  const short* kqbase = qk + qk_head + (size_t)lr * D_ + lk * 8;
  auto kfoff = [&](int i) -> size_t {
    int f = w + 4 * i;
    int kt = (f < c0) ? f : f - c0;
    return (size_t)kt * 16 * D_;
  };
  bf16x8 kreg[4][2];
#pragma unroll
  for (int i = 0; i < 4; ++i) {
    if (i < nfr) {
      const short* p = kqbase + kfoff(i);
      kreg[i][0] = *(const bf16x8*)p;
      kreg[i][1] = *(const bf16x8*)(p + 32);
    }
  }
  __builtin_amdgcn_sched_barrier(0);
#pragma unroll
  for (int i = 0; i < 9; ++i) {
    if (i < nfr) {
      const int f = w + 4 * i;
      __builtin_amdgcn_s_setprio(1);
      if (f < c0) {
#pragma unroll
        for (int ks = 0; ks < 2; ++ks) {
          acc[i][0] = __builtin_amdgcn_mfma_f32_16x16x32_bf16(kreg[i & 3][ks], qf0[0][ks], acc[i][0], 0, 0, 0);
          acc[i][1] = __builtin_amdgcn_mfma_f32_16x16x32_bf16(kreg[i & 3][ks], qf0[1][ks], acc[i][1], 0, 0, 0);
        }
      } else {
#pragma unroll
        for (int ks = 0; ks < 2; ++ks) {
          acc[i][0] = __builtin_amdgcn_mfma_f32_16x16x32_bf16(kreg[i & 3][ks], qf1[0][ks], acc[i][0], 0, 0, 0);
          acc[i][1] = __builtin_amdgcn_mfma_f32_16x16x32_bf16(kreg[i & 3][ks], qf1[1][ks], acc[i][1], 0, 0, 0);
        }
      }
      __builtin_amdgcn_s_setprio(0);
      __builtin_amdgcn_sched_barrier(0); // MFMAs(i) before refill of slot i&3
      if (i + 4 < nfr) {
        const short* p = kqbase + kfoff(i + 4);
        kreg[i & 3][0] = *(const bf16x8*)p;
        kreg[i & 3][1] = *(const bf16x8*)(p + 32);
      }
      __builtin_amdgcn_sched_barrier(0);
    }
  }

  // ---- PV V-prologue: V(0..2) for both units issued NOW (hidden under exp) ----
  const int uqt0 = w & 1, udh0 = w >> 1;
  const int uqt1 = w >> 1, udh1 = w & 1;
  const short* vu0 = vT + (size_t)(h * DK_ + udh0 * 32 + lr) * BS_ + (size_t)b * S_ + lk * 8;
  const short* vu1 = vT + (size_t)(h * DK_ + udh1 * 32 + lr) * BS_ + (size_t)b * S_ + lk * 8;
  bf16x8 vfB[3][2][2];    // [slot][unit][n], slot = kb % 3
#pragma unroll
  for (int kb = 0; kb < 3; ++kb) {
    if (kb < n0) {
#pragma unroll
      for (int n = 0; n < 2; ++n)
        vfB[kb][0][n] = *(const bf16x8*)(vu0 + (size_t)n * 16 * BS_ + kb * 32);
    }
    if (kb < n1) {
#pragma unroll
      for (int n = 0; n < 2; ++n)
        vfB[kb][1][n] = *(const bf16x8*)(vu1 + (size_t)n * 16 * BS_ + kb * 32);
    }
  }
  __builtin_amdgcn_sched_barrier(0);     // V loads in flight before exp pass

  // ---- exp pass: e = (k < q) ? exp(score*frv) : 0 ; b64 P-writes; row sums
  float rs00 = 0.f, rs01 = 0.f, rs10 = 0.f, rs11 = 0.f;
#pragma unroll
  for (int frag = 0; frag < 34; ++frag) {
    if ((frag & 3) == w) {
      const int i = frag >> 2;
      const int tl = (frag < c0) ? 0 : 1;              // compile-time
      const int kt = tl ? frag - c0 : frag;
      const int kbase = kt * 16 + lk * 4;
      const int colb = (tl ? colb1 : 0) + kbase;
#pragma unroll
      for (int qt = 0; qt < 2; ++qt) {
        int qrow = (tl ? qo1 : qo0) + qt * 16 + lr;
        float fv = tl ? frv1[qt] : frv0[qt];
        bf16x4 pk;
        float rs = 0.f;
#pragma unroll
        for (int j = 0; j < 4; ++j) {
          float e = (kbase + j < qrow) ? __expf(acc[i][qt][j] * fv) : 0.f;
          rs += e;
          pk[j] = f2bf(e);
        }
        *(bf16x4*)&Pl[qt * 16 + lr][colb] = pk;
        if (tl == 0) { if (qt == 0) rs00 += rs; else rs01 += rs; }
        else         { if (qt == 0) rs10 += rs; else rs11 += rs; }
      }
    }
  }

#pragma unroll
  for (int msk = 16; msk < 64; msk <<= 1) {
    rs00 += __shfl_xor(rs00, msk);
    rs01 += __shfl_xor(rs01, msk);
    rs10 += __shfl_xor(rs10, msk);
    rs11 += __shfl_xor(rs11, msk);
  }
  if (lk == 0) {
    redsum[0][lr][w] = rs00;
    redsum[0][16 + lr][w] = rs01;
    redsum[1][lr][w] = rs10;
    redsum[1][16 + lr][w] = rs11;
  }
  __syncthreads();   // P + redsum ready (single barrier)

  // ---- PV: ring-3 V pipeline + 1-deep pa(LDS) prefetch ----
  const short* prow0 = &Pl[uqt0 * 16 + lr][lk * 8];
  const short* prow1 = &Pl[uqt1 * 16 + lr][colb1 + lk * 8];
  f32x4 oacc0[2] = {vzero, vzero}, oacc1[2] = {vzero, vzero};
  bf16x8 paB[2][2];       // [parity][unit]
  paB[0][0] = *(const bf16x8*)prow0;
  paB[0][1] = *(const bf16x8*)prow1;

#pragma unroll
  for (int kb = 0; kb < 16; ++kb) {
    const int sc = kb % 3, pc = kb & 1, pn = pc ^ 1;
    if (kb + 1 < n0) paB[pn][0] = *(const bf16x8*)(prow0 + (kb + 1) * 32);
    if (kb + 1 < n1) paB[pn][1] = *(const bf16x8*)(prow1 + (kb + 1) * 32);
    __builtin_amdgcn_sched_barrier(0);
    __builtin_amdgcn_s_setprio(1);
    if (kb < n0) {
#pragma unroll
      for (int n = 0; n < 2; ++n)
        oacc0[n] = __builtin_amdgcn_mfma_f32_16x16x32_bf16(paB[pc][0], vfB[sc][0][n], oacc0[n], 0, 0, 0);
    }
    if (kb < n1) {
#pragma unroll
      for (int n = 0; n < 2; ++n)
        oacc1[n] = __builtin_amdgcn_mfma_f32_16x16x32_bf16(paB[pc][1], vfB[sc][1][n], oacc1[n], 0, 0, 0);
    }
    __builtin_amdgcn_s_setprio(0);
    __builtin_amdgcn_sched_barrier(0);
    if (kb + 3 < n0) {
#pragma unroll
      for (int n = 0; n < 2; ++n)
        vfB[sc][0][n] = *(const bf16x8*)(vu0 + (size_t)n * 16 * BS_ + (kb + 3) * 32);
    }
    if (kb + 3 < n1) {
#pragma unroll
      for (int n = 0; n < 2; ++n)
        vfB[sc][1][n] = *(const bf16x8*)(vu1 + (size_t)n * 16 * BS_ + (kb + 3) * 32);
    }
    __builtin_amdgcn_sched_barrier(0);
  }

  // ---- normalize + write
  {
    float invd[4];
#pragma unroll
    for (int j = 0; j < 4; ++j) {
      int row = uqt0 * 16 + lk * 4 + j;
      float ds = redsum[0][row][0] + redsum[0][row][1] + redsum[0][row][2] + redsum[0][row][3];
      invd[j] = ds > 0.f ? 1.f / ds : 0.f;
    }
#pragma unroll
    for (int n = 0; n < 2; ++n)
#pragma unroll
      for (int j = 0; j < 4; ++j) {
        int qrow = qo0 + uqt0 * 16 + lk * 4 + j;
        out[qk_head + (size_t)qrow * D_ + udh0 * 32 + n * 16 + lr] = f2bf(oacc0[n][j] * invd[j]);
      }
  }
  {
    float invd[4];
#pragma unroll
    for (int j = 0; j < 4; ++j) {
      int row = uqt1 * 16 + lk * 4 + j;
      float ds = redsum[1][row][0] + redsum[1][row][1] + redsum[1][row][2] + redsum[1][row][3];
      invd[j] = ds > 0.f ? 1.f / ds : 0.f;
    }
#pragma unroll
    for (int n = 0; n < 2; ++n)
#pragma unroll
      for (int j = 0; j < 4; ++j) {
        int qrow = qo1 + uqt1 * 16 + lk * 4 + j;
        out[qk_head + (size_t)qrow * D_ + udh1 * 32 + n * 16 + lr] = f2bf(oacc1[n][j] * invd[j]);
      }
  }
}

__global__ __launch_bounds__(256, 3) void attn_kernel(
    const short* __restrict__ qk, const short* __restrict__ vT,
    const float* __restrict__ fr, short* __restrict__ out)
{
  const int hw = blockIdx.x;                 // 4096 blocks
  const int l = (hw & 7) * 512 + (hw >> 3);  // bijective XCD grouping
  const int p = l & 7, hb = l >> 3;
  const int h = hb & 7, b = hb >> 3;
  const int t = threadIdx.x;
  const int w = t >> 6, lr = t & 15, lk = (t & 63) >> 4;

  __shared__ __align__(16) short Pl[32][552];
  __shared__ __align__(16) float redsum[2][32][4];

  switch (p) {
    case 0: attn_body<0>(qk, vT, fr, out, Pl, redsum, h, b, w, lr, lk); break;
    case 1: attn_body<1>(qk, vT, fr, out, Pl, redsum, h, b, w, lr, lk); break;
    case 2: attn_body<2>(qk, vT, fr, out, Pl, redsum, h, b, w, lr, lk); break;
    case 3: attn_body<3>(qk, vT, fr, out, Pl, redsum, h, b, w, lr, lk); break;
    case 4: attn_body<4>(qk, vT, fr, out, Pl, redsum, h, b, w, lr, lk); break;
    case 5: attn_body<5>(qk, vT, fr, out, Pl, redsum, h, b, w, lr, lk); break;
    case 6: attn_body<6>(qk, vT, fr, out, Pl, redsum, h, b, w, lr, lk); break;
    case 7: attn_body<7>(qk, vT, fr, out, Pl, redsum, h, b, w, lr, lk); break;
  }
}

// ---------------- fused residual + LayerNorm (bf16 master) ----------------
template<int FINAL>
__global__ __launch_bounds__(256) void ln_res_t(
    const short* __restrict__ xin, const short* __restrict__ add,
    const float* __restrict__ g, const float* __restrict__ bb,
    short* __restrict__ xbout, float* __restrict__ fout)
{
  const int row = blockIdx.x * 4 + (threadIdx.x >> 6);
  const int lane = threadIdx.x & 63;
  const size_t base = (size_t)row * D_ + lane * 8;

  bf16x8 xv = *(const bf16x8*)(xin + base);
  bf16x8 av = *(const bf16x8*)(add + base);
  float vals[8];
#pragma unroll
  for (int i = 0; i < 8; ++i) vals[i] = bf2f(xv[i]) + bf2f(av[i]);

  float s = 0.f, sq = 0.f;
#pragma unroll
  for (int i = 0; i < 8; ++i) { s += vals[i]; sq += vals[i] * vals[i]; }
#pragma unroll
  for (int m = 1; m < 64; m <<= 1) { s += __shfl_xor(s, m); sq += __shfl_xor(sq, m); }

  float mean = s * (1.f / D_);
  float var = sq * (1.f / D_) - mean * mean;
  float rstd = rsqrtf(var + 1e-5f);

  int col = lane * 8;
  if (FINAL) {
    f32x4 o0, o1;
#pragma unroll
    for (int i = 0; i < 8; ++i) {
      float vv = g[col + i] * (vals[i] - mean) * rstd + bb[col + i];
      if (i < 4) o0[i] = vv; else o1[i - 4] = vv;
    }
    *(f32x4*)(fout + base) = o0;
    *(f32x4*)(fout + base + 4) = o1;
  } else {
    bf16x8 ob;
#pragma unroll
    for (int i = 0; i < 8; ++i)
      ob[i] = f2bf(g[col + i] * (vals[i] - mean) * rstd + bb[col + i]);
    *(bf16x8*)(xbout + base) = ob;
  }
}

// ---------------- host ----------------
extern "C" void kernel_launch(void* const* d_in, const int* in_sizes, int n_in,
                              void* d_out, int out_size, void* d_ws, size_t ws_size,
                              hipStream_t stream) {
  const float* q_emb = (const float*)d_in[0];
  const float* qa_emb = (const float*)d_in[1];
  const float* frate = (const float*)d_in[2];
  const float* Wk = (const float*)d_in[3];
  const float* bk = (const float*)d_in[4];
  const float* Wv = (const float*)d_in[5];
  const float* bv = (const float*)d_in[6];
  const float* Wo = (const float*)d_in[7];
  const float* bo = (const float*)d_in[8];
  const float* ln1g = (const float*)d_in[9];
  const float* ln1b = (const float*)d_in[10];
  const float* W1 = (const float*)d_in[11];
  const float* b1 = (const float*)d_in[12];
  const float* W2 = (const float*)d_in[13];
  const float* b2 = (const float*)d_in[14];
  const float* ln2g = (const float*)d_in[15];
  const float* ln2b = (const float*)d_in[16];
  float* x = (float*)d_out;

  char* ws = (char*)d_ws;
  size_t off = 0;
  auto alloc = [&](size_t bytes) -> void* {
    void* p = ws + off;
    off += (bytes + 255) & ~(size_t)255;
    return p;
  };
  const size_t MTOK = (size_t)BS_;   // 32768 rows
  float* pe    = (float*)alloc((size_t)S_ * D_ * 4);
  short* xb    = (short*)alloc(MTOK * D_ * 2);
  short* yb    = (short*)alloc(MTOK * D_ * 2);
  short* qkb   = (short*)alloc(MTOK * D_ * 2);
  short* vTb   = (short*)alloc(MTOK * D_ * 2);   // V transposed: [D][B*S]
  short* ff1b  = (short*)alloc(MTOK * DFF_ * 2);
  short* attnb = ff1b;
  short* goutb = qkb;
  short* wT[L_][5];
  for (int i = 0; i < L_; ++i) {
    wT[i][0] = (short*)alloc((size_t)D_ * D_ * 2);     // WkT [D][D]
    wT[i][1] = (short*)alloc((size_t)D_ * D_ * 2);     // WvT
    wT[i][2] = (short*)alloc((size_t)D_ * D_ * 2);     // WoT
    wT[i][3] = (short*)alloc((size_t)D_ * DFF_ * 2);   // W1T [DFF][D]
    wT[i][4] = (short*)alloc((size_t)DFF_ * D_ * 2);   // W2T [D][DFF]
  }
  if (off > ws_size) {
    fprintf(stderr, "parKT: workspace overflow: need %zu have %zu\n", off, ws_size);
    return;
  }

  pe_kernel<<<(S_ * D_) / 256, 256, 0, stream>>>(pe);
  prep_kernel<<<(int)(MTOK * D_ / (256 * 8)), 256, 0, stream>>>(q_emb, qa_emb, pe, xb, yb);

  TrArgs ta;
  for (int i = 0; i < L_; ++i) {
    ta.src[i * 5 + 0] = Wk + (size_t)i * D_ * D_;  ta.dst[i * 5 + 0] = wT[i][0]; ta.R[i * 5 + 0] = D_;   ta.C[i * 5 + 0] = D_;
    ta.src[i * 5 + 1] = Wv + (size_t)i * D_ * D_;  ta.dst[i * 5 + 1] = wT[i][1]; ta.R[i * 5 + 1] = D_;   ta.C[i * 5 + 1] = D_;
    ta.src[i * 5 + 2] = Wo + (size_t)i * D_ * D_;  ta.dst[i * 5 + 2] = wT[i][2]; ta.R[i * 5 + 2] = D_;   ta.C[i * 5 + 2] = D_;
    ta.src[i * 5 + 3] = W1 + (size_t)i * D_ * DFF_; ta.dst[i * 5 + 3] = wT[i][3]; ta.R[i * 5 + 3] = D_;   ta.C[i * 5 + 3] = DFF_;
    ta.src[i * 5 + 4] = W2 + (size_t)i * DFF_ * D_; ta.dst[i * 5 + 4] = wT[i][4]; ta.R[i * 5 + 4] = DFF_; ta.C[i * 5 + 4] = D_;
  }
  tr_w_all<<<dim3(DFF_ / 64, DFF_ / 64, 10), 256, 0, stream>>>(ta);

  const int M = (int)MTOK;
  const GArgs gempty = {nullptr, nullptr, nullptr, nullptr, 0, 0, 0, 0, 0, 1, 1, 0};
  for (int i = 0; i < L_; ++i) {
    // MERGED dispatch: qk = x@Wk + bk  AND  vT = WvT@y^T + bv (independent)
    GArgs gqk = {xb, wT[i][0], bk + (size_t)i * D_, qkb,
                 M, D_, D_, 0, 0, D_ / 256, 1, (M / 128) * (D_ / 256)};
    GArgs gvt = {wT[i][1], yb, bv + (size_t)i * D_, vTb,
                 D_, M, D_, 0, 1, M / 256, 0, (D_ / 128) * (M / 256)};
    gemm_bt2<<<gqk.nblk + gvt.nblk, 256, 0, stream>>>(gqk, gvt);

    attn_kernel<<<(S_ / 64) * H_ * B_, 256, 0, stream>>>(qkb, vTb, frate, attnb);

    GArgs gwo = {attnb, wT[i][2], bo + (size_t)i * D_, goutb,
                 M, D_, D_, 0, 0, D_ / 256, 1, (M / 128) * (D_ / 256)};
    gemm_bt2<<<gwo.nblk, 256, 0, stream>>>(gwo, gempty);
    ln_res_t<0><<<M / 4, 256, 0, stream>>>(xb, goutb, ln1g + (size_t)i * D_, ln1b + (size_t)i * D_, xb, nullptr);

    GArgs gf1 = {xb, wT[i][3], b1 + (size_t)i * DFF_, ff1b,
                 M, DFF_, D_, 1, 0, DFF_ / 256, 1, (M / 128) * (DFF_ / 256)};
    gemm_bt2<<<gf1.nblk, 256, 0, stream>>>(gf1, gempty);

    GArgs gf2 = {ff1b, wT[i][4], b2 + (size_t)i * D_, goutb,
                 M, D_, DFF_, 0, 0, D_ / 256, 1, (M / 128) * (D_ / 256)};
    gemm_bt2<<<gf2.nblk, 256, 0, stream>>>(gf2, gempty);

    if (i == L_ - 1)
      ln_res_t<1><<<M / 4, 256, 0, stream>>>(xb, goutb, ln2g + (size_t)i * D_, ln2b + (size_t)i * D_, nullptr, x);
    else
      ln_res_t<0><<<M / 4, 256, 0, stream>>>(xb, goutb, ln2g + (size_t)i * D_, ln2b + (size_t)i * D_, xb, nullptr);
  }
}

// Round 17
// 725.295 us; speedup vs baseline: 1.0134x; 1.0034x over previous
//
#include <hip/hip_runtime.h>
#include <cstdio>

#define B_   64
#define S_   512
#define D_   512
#define H_   8
#define DK_  64
#define DFF_ 1024
#define L_   2
#define BS_  (B_ * S_)   // 32768

typedef __attribute__((ext_vector_type(8))) short bf16x8;
typedef __attribute__((ext_vector_type(4))) short bf16x4;
typedef __attribute__((ext_vector_type(4))) float f32x4;

__device__ inline short f2bf(float f) {
  unsigned u = __float_as_uint(f);
  u = u + 0x7FFF + ((u >> 16) & 1);
  return (short)(u >> 16);
}
__device__ inline float bf2f(short s) {
  return __uint_as_float(((unsigned)(unsigned short)s) << 16);
}

// async global->LDS, 16B per lane; lds dest = wave-uniform base + lane*16
__device__ inline void gl_lds16(const short* g, void* lds_base) {
  __builtin_amdgcn_global_load_lds(
      (const __attribute__((address_space(1))) void*)g,
      (__attribute__((address_space(3))) void*)lds_base, 16, 0, 0);
}

// ---------------- positional encoding table ----------------
__global__ void pe_kernel(float* __restrict__ pe) {
  int idx = blockIdx.x * 256 + threadIdx.x;      // S_*D_ threads
  int s = idx >> 9, d = idx & 511;
  float dv = __expf((float)(d & ~1) * (-9.210340371976184f / (float)D_));
  float ang = (float)s * dv;
  pe[idx] = (d & 1) ? cosf(ang) : sinf(ang);
}

// xb = bf16(q + pe); yb = bf16(qa + pe). 8 elem/thread. (bf16 residual master)
__global__ __launch_bounds__(256) void prep_kernel(
    const float* __restrict__ q, const float* __restrict__ qa,
    const float* __restrict__ pe,
    short* __restrict__ xb, short* __restrict__ yb) {
  size_t base = ((size_t)blockIdx.x * 256 + threadIdx.x) * 8;
  int sd = (int)(base & (size_t)(S_ * D_ - 1));
  f32x4 p0 = *(const f32x4*)(pe + sd);
  f32x4 p1 = *(const f32x4*)(pe + sd + 4);
  f32x4 q0 = *(const f32x4*)(q + base);
  f32x4 q1 = *(const f32x4*)(q + base + 4);
  f32x4 a0 = *(const f32x4*)(qa + base);
  f32x4 a1 = *(const f32x4*)(qa + base + 4);
  bf16x8 xv, yv;
#pragma unroll
  for (int i = 0; i < 4; ++i) {
    xv[i] = f2bf(q0[i] + p0[i]);
    yv[i] = f2bf(a0[i] + p0[i]);
  }
#pragma unroll
  for (int i = 0; i < 4; ++i) {
    xv[4 + i] = f2bf(q1[i] + p1[i]);
    yv[4 + i] = f2bf(a1[i] + p1[i]);
  }
  *(bf16x8*)(xb + base) = xv;
  *(bf16x8*)(yb + base) = yv;
}

// ---------------- all weight transposes in ONE launch ----------------
struct TrArgs {
  const float* src[10];
  short* dst[10];
  int R[10], C[10];
};
__global__ __launch_bounds__(256) void tr_w_all(TrArgs a) {
  const int slot = blockIdx.z;
  const int R = a.R[slot], C = a.C[slot];
  const int c0 = blockIdx.x * 64, r0 = blockIdx.y * 64;
  if (c0 >= C || r0 >= R) return;
  const float* __restrict__ src = a.src[slot];
  short* __restrict__ dst = a.dst[slot];
  __shared__ short Ts[64][72];
  const int t = threadIdx.x;
#pragma unroll
  for (int it = 0; it < 2; ++it) {
    int c2 = it * 256 + t;
    int srow = c2 >> 3, schunk = c2 & 7;
    const float* sp = src + (size_t)(r0 + srow) * C + c0 + schunk * 8;
    f32x4 a0 = *(const f32x4*)sp;
    f32x4 a1 = *(const f32x4*)(sp + 4);
#pragma unroll
    for (int k = 0; k < 4; ++k) Ts[srow][schunk * 8 + k] = f2bf(a0[k]);
#pragma unroll
    for (int k = 0; k < 4; ++k) Ts[srow][schunk * 8 + 4 + k] = f2bf(a1[k]);
  }
  __syncthreads();
#pragma unroll
  for (int it = 0; it < 2; ++it) {
    int c2 = it * 256 + t;
    int orow = c2 >> 3, ochunk = c2 & 7;
    bf16x8 vv;
#pragma unroll
    for (int k = 0; k < 8; ++k) vv[k] = Ts[ochunk * 8 + k][orow];
    *(bf16x8*)(dst + (size_t)(c0 + orow) * R + r0 + ochunk * 8) = vv;
  }
}

// ---------------- bf16 MFMA GEMM (dual-slot, 8-phase): C = A @ BT^T + bias ------
// 256x256 tile, BK=64, 8 waves (2Mx4N), K-SPLIT phase schedule:
//   tile entry:  vmcnt(4) + barrier   (k0 halves of tile t landed; k1 may fly)
//   ph0: stage A-k0(t+1) | ds_read B,A(m0-3) kk0 | 16 MFMA
//   ph1: stage B-k0(t+1) | ds_read A(m4-7) kk0   | 16 MFMA
//   kk1 entry:   vmcnt(4|0) + barrier (tile t's k1 landed; t+1's k0 may fly)
//   ph2: stage A-k1(t+1) | ds_read B,A(m0-3) kk1 | 16 MFMA
//   ph3: stage B-k1(t+1) | ds_read A(m4-7) kk1   | 16 MFMA
// Counted vmcnt never drains mid-loop (T4). Swizzle chunk^=(row>>1)&3 via
// pre-swizzled global source (rule #21). Swapped-operand MFMA -> b64 col stores.
// XCD-aware remap over combined grid; two independent GEMMs may share a dispatch.
struct GArgs {
  const short* A; const short* BT; const float* bias; short* Cb;
  int M, N, K, relu, bias_row, nx, xmaj, nblk;
};
__global__ __launch_bounds__(512, 2) void gemm_bt2(GArgs g0, GArgs g1)
{
  const int nwg = gridDim.x;                 // multiple of 8
  const int cpx = nwg >> 3;
  const int l = (blockIdx.x & 7) * cpx + (blockIdx.x >> 3);

  const short* A; const short* BT; const float* bias; short* Cb;
  int N, K, relu, bias_row, nx, xmaj, ll, nb;
  if (l < g0.nblk) {
    A = g0.A; BT = g0.BT; bias = g0.bias; Cb = g0.Cb;
    N = g0.N; K = g0.K; relu = g0.relu; bias_row = g0.bias_row;
    nx = g0.nx; xmaj = g0.xmaj; ll = l; nb = g0.nblk;
  } else {
    A = g1.A; BT = g1.BT; bias = g1.bias; Cb = g1.Cb;
    N = g1.N; K = g1.K; relu = g1.relu; bias_row = g1.bias_row;
    nx = g1.nx; xmaj = g1.xmaj; ll = l - g0.nblk; nb = g1.nblk;
  }
  int bcol, brow;
  if (xmaj) { bcol = ll % nx; brow = ll / nx; }
  else      { int ny = nb / nx; brow = ll % ny; bcol = ll / ny; }

  __shared__ __align__(16) short As[2][16384];   // [buf][kk*8192 + row*32 + col]
  __shared__ __align__(16) short Bs[2][16384];
  const int t = threadIdx.x;                 // 0..511
  const int w = t >> 6, lane = t & 63, lr = lane & 15, lk = lane >> 4;
  const int wm = w >> 2, wn = w & 3;         // 2 x 4 wave grid

  const f32x4 vzero = {0.f, 0.f, 0.f, 0.f};
  f32x4 acc[8][4];
#pragma unroll
  for (int m = 0; m < 8; ++m)
#pragma unroll
    for (int n = 0; n < 4; ++n) acc[m][n] = vzero;

  const short* Abase = A + (size_t)brow * 256 * K;
  const short* Bbase = BT + (size_t)bcol * 256 * K;

  // stage K-half kk of a tile at k0 into ldsbuf; linear dest, pre-swizzled source
  auto stageH = [&](short* ldsbuf, const short* gsrc, int kk, int k0) {
#pragma unroll
    for (int it = 0; it < 2; ++it) {
      int c = it * 512 + t;                // chunk id 0..1023 (4 chunks/row)
      int cb = it * 512 + w * 64;          // wave-uniform chunk base
      int row = c >> 2, pos = c & 3;
      int gc = pos ^ ((row >> 1) & 3);     // pre-swizzled source chunk
      gl_lds16(gsrc + (size_t)row * K + k0 + kk * 32 + gc * 8,
               (char*)ldsbuf + (size_t)(kk * 1024 + cb) * 16);
    }
  };
  // swizzled read of fragment at (row, kk); lane chunk = lk ^ ((row>>1)&3)
  auto ldfrag = [&](const short* ldsbuf, int kk, int row) -> bf16x8 {
    int chunk = kk * 1024 + row * 4 + (lk ^ ((row >> 1) & 3));
    return *(const bf16x8*)((const char*)ldsbuf + (size_t)chunk * 16);
  };

  const int T = K >> 6;
  // prologue: tile 0, order A-k0, B-k0, A-k1, B-k1 (8 loads/thread)
  stageH(As[0], Abase, 0, 0);
  stageH(Bs[0], Bbase, 0, 0);
  stageH(As[0], Abase, 1, 0);
  stageH(Bs[0], Bbase, 1, 0);

  for (int ti = 0; ti < T; ++ti) {
    const int cbuf = ti & 1, obuf = cbuf ^ 1;
    const int k1 = (ti + 1) * 64;
    const bool more = (ti + 1 < T);

    asm volatile("s_waitcnt vmcnt(4)" ::: "memory");  // tile ti k0 landed
    asm volatile("s_barrier" ::: "memory");

    // ---- kk = 0 ----
    if (more) stageH(As[obuf], Abase, 0, k1);         // phase 0 stage
    bf16x8 bf[4], af[4];
#pragma unroll
    for (int n = 0; n < 4; ++n) bf[n] = ldfrag(Bs[cbuf], 0, wn * 64 + n * 16 + lr);
#pragma unroll
    for (int m = 0; m < 4; ++m) af[m] = ldfrag(As[cbuf], 0, wm * 128 + m * 16 + lr);
    __builtin_amdgcn_sched_barrier(0);
    __builtin_amdgcn_s_setprio(1);
#pragma unroll
    for (int m = 0; m < 4; ++m)
#pragma unroll
      for (int n = 0; n < 4; ++n)
        acc[m][n] = __builtin_amdgcn_mfma_f32_16x16x32_bf16(bf[n], af[m], acc[m][n], 0, 0, 0);
    __builtin_amdgcn_s_setprio(0);
    __builtin_amdgcn_sched_barrier(0);

    if (more) stageH(Bs[obuf], Bbase, 0, k1);         // phase 1 stage
#pragma unroll
    for (int m = 0; m < 4; ++m) af[m] = ldfrag(As[cbuf], 0, wm * 128 + (m + 4) * 16 + lr);
    __builtin_amdgcn_sched_barrier(0);
    __builtin_amdgcn_s_setprio(1);
#pragma unroll
    for (int m = 0; m < 4; ++m)
#pragma unroll
      for (int n = 0; n < 4; ++n)
        acc[m + 4][n] = __builtin_amdgcn_mfma_f32_16x16x32_bf16(bf[n], af[m], acc[m + 4][n], 0, 0, 0);
    __builtin_amdgcn_s_setprio(0);
    __builtin_amdgcn_sched_barrier(0);

    // ---- kk = 1 ----
    if (more) asm volatile("s_waitcnt vmcnt(4)" ::: "memory");  // ti's k1 landed
    else      asm volatile("s_waitcnt vmcnt(0)" ::: "memory");
    asm volatile("s_barrier" ::: "memory");

    if (more) stageH(As[obuf], Abase, 1, k1);         // phase 2 stage
#pragma unroll
    for (int n = 0; n < 4; ++n) bf[n] = ldfrag(Bs[cbuf], 1, wn * 64 + n * 16 + lr);
#pragma unroll
    for (int m = 0; m < 4; ++m) af[m] = ldfrag(As[cbuf], 1, wm * 128 + m * 16 + lr);
    __builtin_amdgcn_sched_barrier(0);
    __builtin_amdgcn_s_setprio(1);
#pragma unroll
    for (int m = 0; m < 4; ++m)
#pragma unroll
      for (int n = 0; n < 4; ++n)
        acc[m][n] = __builtin_amdgcn_mfma_f32_16x16x32_bf16(bf[n], af[m], acc[m][n], 0, 0, 0);
    __builtin_amdgcn_s_setprio(0);
    __builtin_amdgcn_sched_barrier(0);

    if (more) stageH(Bs[obuf], Bbase, 1, k1);         // phase 3 stage
#pragma unroll
    for (int m = 0; m < 4; ++m) af[m] = ldfrag(As[cbuf], 1, wm * 128 + (m + 4) * 16 + lr);
    __builtin_amdgcn_sched_barrier(0);
    __builtin_amdgcn_s_setprio(1);
#pragma unroll
    for (int m = 0; m < 4; ++m)
#pragma unroll
      for (int n = 0; n < 4; ++n)
        acc[m + 4][n] = __builtin_amdgcn_mfma_f32_16x16x32_bf16(bf[n], af[m], acc[m + 4][n], 0, 0, 0);
    __builtin_amdgcn_s_setprio(0);
    __builtin_amdgcn_sched_barrier(0);
  }

#pragma unroll
  for (int m = 0; m < 8; ++m) {
    int row = brow * 256 + wm * 128 + m * 16 + lr;
    float brv = (bias && bias_row) ? bias[row] : 0.f;
    size_t rb = (size_t)row * N;
#pragma unroll
    for (int n = 0; n < 4; ++n) {
      int colb = bcol * 256 + wn * 64 + n * 16 + lk * 4;
      f32x4 bv4;
      if (bias && !bias_row) bv4 = *(const f32x4*)(bias + colb);
      else { bv4[0] = brv; bv4[1] = brv; bv4[2] = brv; bv4[3] = brv; }
      bf16x4 ov;
#pragma unroll
      for (int j = 0; j < 4; ++j) {
        float vv = acc[m][n][j] + bv4[j];
        if (relu) vv = fmaxf(vv, 0.f);
        ov[j] = f2bf(vv);
      }
      *(bf16x4*)(Cb + rb + colb) = ov;   // 8B store, 4 lanes/row contiguous 32B
    }
  }
}

// ---------------- fused attention (best-measured r11 variant) ----------------
template<int P>
__device__ __forceinline__ void attn_body(
    const short* __restrict__ qk, const short* __restrict__ vT,
    const float* __restrict__ fr, short* __restrict__ out,
    short (*Pl)[552], float (*redsum)[32][4],
    int h, int b, int w, int lr, int lk)
{
  constexpr int qo0 = 32 * P, qo1 = 32 * (15 - P);
  constexpr int c0 = 2 * P + 2;          // tile0 fragment count
  constexpr int colb1 = c0 * 16;         // tile1 P-column offset
  constexpr int n0 = P + 1;              // unit0 PV kb count
  constexpr int n1 = 16 - P;             // unit1 PV kb count

  const size_t qk_head = (size_t)b * S_ * D_ + (size_t)h * DK_;
  const float scale = 0.125f;   // 1/sqrt(64)

  bf16x8 qf0[2][2], qf1[2][2];   // [qt][ks]
#pragma unroll
  for (int qt = 0; qt < 2; ++qt)
#pragma unroll
    for (int ks = 0; ks < 2; ++ks) {
      qf0[qt][ks] = *(const bf16x8*)(qk + qk_head + (size_t)(qo0 + qt * 16 + lr) * D_ + ks * 32 + lk * 8);
      qf1[qt][ks] = *(const bf16x8*)(qk + qk_head + (size_t)(qo1 + qt * 16 + lr) * D_ + ks * 32 + lk * 8);
    }

  float frv0[2], frv1[2];
#pragma unroll
  for (int qt = 0; qt < 2; ++qt) {
    frv0[qt] = scale * fr[(size_t)b * S_ + qo0 + qt * 16 + lr];
    frv1[qt] = scale * fr[(size_t)b * S_ + qo1 + qt * 16 + lr];
  }

  const f32x4 vzero = {0.f, 0.f, 0.f, 0.f};
  f32x4 acc[9][2];
#pragma unroll
  for (int i = 0; i < 9; ++i) { acc[i][0] = vzero; acc[i][1] = vzero; }

  // ---- QK^T (swapped), ring-4 K prefetch
  const int nfr = (w < 2) ? 9 : 8;     // 34 fragments over 4 waves
  const short* kqbase = qk + qk_head + (size_t)lr * D_ + lk * 8;
  auto kfoff = [&](int i) -> size_t {
    int f = w + 4 * i;
    int kt = (f < c0) ? f : f - c0;
    return (size_t)kt * 16 * D_;
  };
  bf16x8 kreg[4][2];
#pragma unroll
  for (int i = 0; i < 4; ++i) {
    if (i < nfr) {
      const short* p = kqbase + kfoff(i);
      kreg[i][0] = *(const bf16x8*)p;
      kreg[i][1] = *(const bf16x8*)(p + 32);
    }
  }
  __builtin_amdgcn_sched_barrier(0);
#pragma unroll
  for (int i = 0; i < 9; ++i) {
    if (i < nfr) {
      const int f = w + 4 * i;
      __builtin_amdgcn_s_setprio(1);
      if (f < c0) {
#pragma unroll
        for (int ks = 0; ks < 2; ++ks) {
          acc[i][0] = __builtin_amdgcn_mfma_f32_16x16x32_bf16(kreg[i & 3][ks], qf0[0][ks], acc[i][0], 0, 0, 0);
          acc[i][1] = __builtin_amdgcn_mfma_f32_16x16x32_bf16(kreg[i & 3][ks], qf0[1][ks], acc[i][1], 0, 0, 0);
        }
      } else {
#pragma unroll
        for (int ks = 0; ks < 2; ++ks) {
          acc[i][0] = __builtin_amdgcn_mfma_f32_16x16x32_bf16(kreg[i & 3][ks], qf1[0][ks], acc[i][0], 0, 0, 0);
          acc[i][1] = __builtin_amdgcn_mfma_f32_16x16x32_bf16(kreg[i & 3][ks], qf1[1][ks], acc[i][1], 0, 0, 0);
        }
      }
      __builtin_amdgcn_s_setprio(0);
      __builtin_amdgcn_sched_barrier(0); // MFMAs(i) before refill of slot i&3
      if (i + 4 < nfr) {
        const short* p = kqbase + kfoff(i + 4);
        kreg[i & 3][0] = *(const bf16x8*)p;
        kreg[i & 3][1] = *(const bf16x8*)(p + 32);
      }
      __builtin_amdgcn_sched_barrier(0);
    }
  }

  // ---- PV V-prologue: V(0..2) for both units issued NOW (hidden under exp) ----
  const int uqt0 = w & 1, udh0 = w >> 1;
  const int uqt1 = w >> 1, udh1 = w & 1;
  const short* vu0 = vT + (size_t)(h * DK_ + udh0 * 32 + lr) * BS_ + (size_t)b * S_ + lk * 8;
  const short* vu1 = vT + (size_t)(h * DK_ + udh1 * 32 + lr) * BS_ + (size_t)b * S_ + lk * 8;
  bf16x8 vfB[3][2][2];    // [slot][unit][n], slot = kb % 3
#pragma unroll
  for (int kb = 0; kb < 3; ++kb) {
    if (kb < n0) {
#pragma unroll
      for (int n = 0; n < 2; ++n)
        vfB[kb][0][n] = *(const bf16x8*)(vu0 + (size_t)n * 16 * BS_ + kb * 32);
    }
    if (kb < n1) {
#pragma unroll
      for (int n = 0; n < 2; ++n)
        vfB[kb][1][n] = *(const bf16x8*)(vu1 + (size_t)n * 16 * BS_ + kb * 32);
    }
  }
  __builtin_amdgcn_sched_barrier(0);     // V loads in flight before exp pass

  // ---- exp pass: e = (k < q) ? exp(score*frv) : 0 ; b64 P-writes; row sums
  float rs00 = 0.f, rs01 = 0.f, rs10 = 0.f, rs11 = 0.f;
#pragma unroll
  for (int frag = 0; frag < 34; ++frag) {
    if ((frag & 3) == w) {
      const int i = frag >> 2;
      const int tl = (frag < c0) ? 0 : 1;              // compile-time
      const int kt = tl ? frag - c0 : frag;
      const int kbase = kt * 16 + lk * 4;
      const int colb = (tl ? colb1 : 0) + kbase;
#pragma unroll
      for (int qt = 0; qt < 2; ++qt) {
        int qrow = (tl ? qo1 : qo0) + qt * 16 + lr;
        float fv = tl ? frv1[qt] : frv0[qt];
        bf16x4 pk;
        float rs = 0.f;
#pragma unroll
        for (int j = 0; j < 4; ++j) {
          float e = (kbase + j < qrow) ? __expf(acc[i][qt][j] * fv) : 0.f;
          rs += e;
          pk[j] = f2bf(e);
        }
        *(bf16x4*)&Pl[qt * 16 + lr][colb] = pk;
        if (tl == 0) { if (qt == 0) rs00 += rs; else rs01 += rs; }
        else         { if (qt == 0) rs10 += rs; else rs11 += rs; }
      }
    }
  }

#pragma unroll
  for (int msk = 16; msk < 64; msk <<= 1) {
    rs00 += __shfl_xor(rs00, msk);
    rs01 += __shfl_xor(rs01, msk);
    rs10 += __shfl_xor(rs10, msk);
    rs11 += __shfl_xor(rs11, msk);
  }
  if (lk == 0) {
    redsum[0][lr][w] = rs00;
    redsum[0][16 + lr][w] = rs01;
    redsum[1][lr][w] = rs10;
    redsum[1][16 + lr][w] = rs11;
  }
  __syncthreads();   // P + redsum ready (single barrier)

  // ---- PV: ring-3 V pipeline + 1-deep pa(LDS) prefetch ----
  const short* prow0 = &Pl[uqt0 * 16 + lr][lk * 8];
  const short* prow1 = &Pl[uqt1 * 16 + lr][colb1 + lk * 8];
  f32x4 oacc0[2] = {vzero, vzero}, oacc1[2] = {vzero, vzero};
  bf16x8 paB[2][2];       // [parity][unit]
  paB[0][0] = *(const bf16x8*)prow0;
  paB[0][1] = *(const bf16x8*)prow1;

#pragma unroll
  for (int kb = 0; kb < 16; ++kb) {
    const int sc = kb % 3, pc = kb & 1, pn = pc ^ 1;
    if (kb + 1 < n0) paB[pn][0] = *(const bf16x8*)(prow0 + (kb + 1) * 32);
    if (kb + 1 < n1) paB[pn][1] = *(const bf16x8*)(prow1 + (kb + 1) * 32);
    __builtin_amdgcn_sched_barrier(0);
    __builtin_amdgcn_s_setprio(1);
    if (kb < n0) {
#pragma unroll
      for (int n = 0; n < 2; ++n)
        oacc0[n] = __builtin_amdgcn_mfma_f32_16x16x32_bf16(paB[pc][0], vfB[sc][0][n], oacc0[n], 0, 0, 0);
    }
    if (kb < n1) {
#pragma unroll
      for (int n = 0; n < 2; ++n)
        oacc1[n] = __builtin_amdgcn_mfma_f32_16x16x32_bf16(paB[pc][1], vfB[sc][1][n], oacc1[n], 0, 0, 0);
    }
    __builtin_amdgcn_s_setprio(0);
    __builtin_amdgcn_sched_barrier(0);
    if (kb + 3 < n0) {
#pragma unroll
      for (int n = 0; n < 2; ++n)
        vfB[sc][0][n] = *(const bf16x8*)(vu0 + (size_t)n * 16 * BS_ + (kb + 3) * 32);
    }
    if (kb + 3 < n1) {
#pragma unroll
      for (int n = 0; n < 2; ++n)
        vfB[sc][1][n] = *(const bf16x8*)(vu1 + (size_t)n * 16 * BS_ + (kb + 3) * 32);
    }
    __builtin_amdgcn_sched_barrier(0);
  }

  // ---- normalize + write
  {
    float invd[4];
#pragma unroll
    for (int j = 0; j < 4; ++j) {
      int row = uqt0 * 16 + lk * 4 + j;
      float ds = redsum[0][row][0] + redsum[0][row][1] + redsum[0][row][2] + redsum[0][row][3];
      invd[j] = ds > 0.f ? 1.f / ds : 0.f;
    }
#pragma unroll
    for (int n = 0; n < 2; ++n)
#pragma unroll
      for (int j = 0; j < 4; ++j) {
        int qrow = qo0 + uqt0 * 16 + lk * 4 + j;
        out[qk_head + (size_t)qrow * D_ + udh0 * 32 + n * 16 + lr] = f2bf(oacc0[n][j] * invd[j]);
      }
  }
  {
    float invd[4];
#pragma unroll
    for (int j = 0; j < 4; ++j) {
      int row = uqt1 * 16 + lk * 4 + j;
      float ds = redsum[1][row][0] + redsum[1][row][1] + redsum[1][row][2] + redsum[1][row][3];
      invd[j] = ds > 0.f ? 1.f / ds : 0.f;
    }
#pragma unroll
    for (int n = 0; n < 2; ++n)
#pragma unroll
      for (int j = 0; j < 4; ++j) {
        int qrow = qo1 + uqt1 * 16 + lk * 4 + j;
        out[qk_head + (size_t)qrow * D_ + udh1 * 32 + n * 16 + lr] = f2bf(oacc1[n][j] * invd[j]);
      }
  }
}

__global__ __launch_bounds__(256, 3) void attn_kernel(
    const short* __restrict__ qk, const short* __restrict__ vT,
    const float* __restrict__ fr, short* __restrict__ out)
{
  const int hw = blockIdx.x;                 // 4096 blocks
  const int l = (hw & 7) * 512 + (hw >> 3);  // bijective XCD grouping
  const int p = l & 7, hb = l >> 3;
  const int h = hb & 7, b = hb >> 3;
  const int t = threadIdx.x;
  const int w = t >> 6, lr = t & 15, lk = (t & 63) >> 4;

  __shared__ __align__(16) short Pl[32][552];
  __shared__ __align__(16) float redsum[2][32][4];

  switch (p) {
    case 0: attn_body<0>(qk, vT, fr, out, Pl, redsum, h, b, w, lr, lk); break;
    case 1: attn_body<1>(qk, vT, fr, out, Pl, redsum, h, b, w, lr, lk); break;
    case 2: attn_body<2>(qk, vT, fr, out, Pl, redsum, h, b, w, lr, lk); break;
    case 3: attn_body<3>(qk, vT, fr, out, Pl, redsum, h, b, w, lr, lk); break;
    case 4: attn_body<4>(qk, vT, fr, out, Pl, redsum, h, b, w, lr, lk); break;
    case 5: attn_body<5>(qk, vT, fr, out, Pl, redsum, h, b, w, lr, lk); break;
    case 6: attn_body<6>(qk, vT, fr, out, Pl, redsum, h, b, w, lr, lk); break;
    case 7: attn_body<7>(qk, vT, fr, out, Pl, redsum, h, b, w, lr, lk); break;
  }
}

// ---------------- fused residual + LayerNorm (bf16 master) ----------------
template<int FINAL>
__global__ __launch_bounds__(256) void ln_res_t(
    const short* __restrict__ xin, const short* __restrict__ add,
    const float* __restrict__ g, const float* __restrict__ bb,
    short* __restrict__ xbout, float* __restrict__ fout)
{
  const int row = blockIdx.x * 4 + (threadIdx.x >> 6);
  const int lane = threadIdx.x & 63;
  const size_t base = (size_t)row * D_ + lane * 8;

  bf16x8 xv = *(const bf16x8*)(xin + base);
  bf16x8 av = *(const bf16x8*)(add + base);
  float vals[8];
#pragma unroll
  for (int i = 0; i < 8; ++i) vals[i] = bf2f(xv[i]) + bf2f(av[i]);

  float s = 0.f, sq = 0.f;
#pragma unroll
  for (int i = 0; i < 8; ++i) { s += vals[i]; sq += vals[i] * vals[i]; }
#pragma unroll
  for (int m = 1; m < 64; m <<= 1) { s += __shfl_xor(s, m); sq += __shfl_xor(sq, m); }

  float mean = s * (1.f / D_);
  float var = sq * (1.f / D_) - mean * mean;
  float rstd = rsqrtf(var + 1e-5f);

  int col = lane * 8;
  if (FINAL) {
    f32x4 o0, o1;
#pragma unroll
    for (int i = 0; i < 8; ++i) {
      float vv = g[col + i] * (vals[i] - mean) * rstd + bb[col + i];
      if (i < 4) o0[i] = vv; else o1[i - 4] = vv;
    }
    *(f32x4*)(fout + base) = o0;
    *(f32x4*)(fout + base + 4) = o1;
  } else {
    bf16x8 ob;
#pragma unroll
    for (int i = 0; i < 8; ++i)
      ob[i] = f2bf(g[col + i] * (vals[i] - mean) * rstd + bb[col + i]);
    *(bf16x8*)(xbout + base) = ob;
  }
}

// ---------------- host ----------------
extern "C" void kernel_launch(void* const* d_in, const int* in_sizes, int n_in,
                              void* d_out, int out_size, void* d_ws, size_t ws_size,
                              hipStream_t stream) {
  const float* q_emb = (const float*)d_in[0];
  const float* qa_emb = (const float*)d_in[1];
  const float* frate = (const float*)d_in[2];
  const float* Wk = (const float*)d_in[3];
  const float* bk = (const float*)d_in[4];
  const float* Wv = (const float*)d_in[5];
  const float* bv = (const float*)d_in[6];
  const float* Wo = (const float*)d_in[7];
  const float* bo = (const float*)d_in[8];
  const float* ln1g = (const float*)d_in[9];
  const float* ln1b = (const float*)d_in[10];
  const float* W1 = (const float*)d_in[11];
  const float* b1 = (const float*)d_in[12];
  const float* W2 = (const float*)d_in[13];
  const float* b2 = (const float*)d_in[14];
  const float* ln2g = (const float*)d_in[15];
  const float* ln2b = (const float*)d_in[16];
  float* x = (float*)d_out;

  char* ws = (char*)d_ws;
  size_t off = 0;
  auto alloc = [&](size_t bytes) -> void* {
    void* p = ws + off;
    off += (bytes + 255) & ~(size_t)255;
    return p;
  };
  const size_t MTOK = (size_t)BS_;   // 32768 rows
  float* pe    = (float*)alloc((size_t)S_ * D_ * 4);
  short* xb    = (short*)alloc(MTOK * D_ * 2);
  short* yb    = (short*)alloc(MTOK * D_ * 2);
  short* qkb   = (short*)alloc(MTOK * D_ * 2);
  short* vTb   = (short*)alloc(MTOK * D_ * 2);   // V transposed: [D][B*S]
  short* ff1b  = (short*)alloc(MTOK * DFF_ * 2);
  short* attnb = ff1b;
  short* goutb = qkb;
  short* wT[L_][5];
  for (int i = 0; i < L_; ++i) {
    wT[i][0] = (short*)alloc((size_t)D_ * D_ * 2);     // WkT [D][D]
    wT[i][1] = (short*)alloc((size_t)D_ * D_ * 2);     // WvT
    wT[i][2] = (short*)alloc((size_t)D_ * D_ * 2);     // WoT
    wT[i][3] = (short*)alloc((size_t)D_ * DFF_ * 2);   // W1T [DFF][D]
    wT[i][4] = (short*)alloc((size_t)DFF_ * D_ * 2);   // W2T [D][DFF]
  }
  if (off > ws_size) {
    fprintf(stderr, "parKT: workspace overflow: need %zu have %zu\n", off, ws_size);
    return;
  }

  pe_kernel<<<(S_ * D_) / 256, 256, 0, stream>>>(pe);
  prep_kernel<<<(int)(MTOK * D_ / (256 * 8)), 256, 0, stream>>>(q_emb, qa_emb, pe, xb, yb);

  TrArgs ta;
  for (int i = 0; i < L_; ++i) {
    ta.src[i * 5 + 0] = Wk + (size_t)i * D_ * D_;  ta.dst[i * 5 + 0] = wT[i][0]; ta.R[i * 5 + 0] = D_;   ta.C[i * 5 + 0] = D_;
    ta.src[i * 5 + 1] = Wv + (size_t)i * D_ * D_;  ta.dst[i * 5 + 1] = wT[i][1]; ta.R[i * 5 + 1] = D_;   ta.C[i * 5 + 1] = D_;
    ta.src[i * 5 + 2] = Wo + (size_t)i * D_ * D_;  ta.dst[i * 5 + 2] = wT[i][2]; ta.R[i * 5 + 2] = D_;   ta.C[i * 5 + 2] = D_;
    ta.src[i * 5 + 3] = W1 + (size_t)i * D_ * DFF_; ta.dst[i * 5 + 3] = wT[i][3]; ta.R[i * 5 + 3] = D_;   ta.C[i * 5 + 3] = DFF_;
    ta.src[i * 5 + 4] = W2 + (size_t)i * DFF_ * D_; ta.dst[i * 5 + 4] = wT[i][4]; ta.R[i * 5 + 4] = DFF_; ta.C[i * 5 + 4] = D_;
  }
  tr_w_all<<<dim3(DFF_ / 64, DFF_ / 64, 10), 256, 0, stream>>>(ta);

  const int M = (int)MTOK;
  const GArgs gempty = {nullptr, nullptr, nullptr, nullptr, 0, 0, 0, 0, 0, 1, 1, 0};
  for (int i = 0; i < L_; ++i) {
    // MERGED dispatch: qk = x@Wk + bk  AND  vT = WvT@y^T + bv (independent)
    GArgs gqk = {xb, wT[i][0], bk + (size_t)i * D_, qkb,
                 M, D_, D_, 0, 0, D_ / 256, 1, (M / 256) * (D_ / 256)};
    GArgs gvt = {wT[i][1], yb, bv + (size_t)i * D_, vTb,
                 D_, M, D_, 0, 1, (D_ / 256) * (M / 256) / (D_ / 256), 0, (D_ / 256) * (M / 256)};
    // xmaj=0: ny = nblk/nx = D_/256 (#brow tiles) -> nx = nblk / (D_/256)
    gvt.nx = gvt.nblk / (D_ / 256);
    gemm_bt2<<<gqk.nblk + gvt.nblk, 512, 0, stream>>>(gqk, gvt);

    attn_kernel<<<(S_ / 64) * H_ * B_, 256, 0, stream>>>(qkb, vTb, frate, attnb);

    GArgs gwo = {attnb, wT[i][2], bo + (size_t)i * D_, goutb,
                 M, D_, D_, 0, 0, D_ / 256, 1, (M / 256) * (D_ / 256)};
    gemm_bt2<<<gwo.nblk, 512, 0, stream>>>(gwo, gempty);
    ln_res_t<0><<<M / 4, 256, 0, stream>>>(xb, goutb, ln1g + (size_t)i * D_, ln1b + (size_t)i * D_, xb, nullptr);

    GArgs gf1 = {xb, wT[i][3], b1 + (size_t)i * DFF_, ff1b,
                 M, DFF_, D_, 1, 0, DFF_ / 256, 1, (M / 256) * (DFF_ / 256)};
    gemm_bt2<<<gf1.nblk, 512, 0, stream>>>(gf1, gempty);

    GArgs gf2 = {ff1b, wT[i][4], b2 + (size_t)i * D_, goutb,
                 M, D_, DFF_, 0, 0, D_ / 256, 1, (M / 256) * (D_ / 256)};
    gemm_bt2<<<gf2.nblk, 512, 0, stream>>>(gf2, gempty);

    if (i == L_ - 1)
      ln_res_t<1><<<M / 4, 256, 0, stream>>>(xb, goutb, ln2g + (size_t)i * D_, ln2b + (size_t)i * D_, nullptr, x);
    else
      ln_res_t<0><<<M / 4, 256, 0, stream>>>(xb, goutb, ln2g + (size_t)i * D_, ln2b + (size_t)i * D_, xb, nullptr);
  }
}